// Round 1
// baseline (281.976 us; speedup 1.0000x reference)
//
#include <hip/hip_runtime.h>
#include <hip/hip_bf16.h>
#include <cstdint>
#include <cstddef>

typedef __bf16 bf16;
typedef bf16 bf16x8 __attribute__((ext_vector_type(8)));
typedef bf16 bf16x2 __attribute__((ext_vector_type(2)));
typedef float f32x4 __attribute__((ext_vector_type(4)));

#define MFMA16(A, B, Cc) __builtin_amdgcn_mfma_f32_16x16x32_bf16((A), (B), (Cc), 0, 0, 0)

static constexpr int L   = 4096;  // H*W
static constexpr int CH  = 256;   // channels
static constexpr int NH  = 4;     // heads
static constexpr int DK  = 64;    // head dim

// workspace layout (bytes), all 16B aligned
static constexpr size_t OFF_WALL = 0;         // 768*256 bf16  (Wq|Wk|Wv rows)
static constexpr size_t OFF_WMB  = 393216;    // 256*256 bf16
static constexpr size_t OFF_BALL = 524288;    // 768 f32       (bq|bk|bv)
static constexpr size_t OFF_XT   = 527360;    // [B][L][C] bf16
static constexpr size_t OFF_QT   = 4721664;   // [B][H][L][64] bf16 (normalized)
static constexpr size_t OFF_KT   = 8915968;   // [B][H][L][64] bf16 (normalized)
static constexpr size_t OFF_VD   = 13110272;  // [B][H][64][L] bf16
static constexpr size_t OFF_RT   = 17304576;  // [B][L][256] bf16 (attn out, heads concat)

// ---------------- kernel 0: weight/bias conversion ----------------
__global__ __launch_bounds__(256) void k_wcvt(
    const float* __restrict__ Wq, const float* __restrict__ Wk,
    const float* __restrict__ Wv, const float* __restrict__ bq,
    const float* __restrict__ bk, const float* __restrict__ bv,
    const float* __restrict__ Wm, bf16* __restrict__ Wall,
    float* __restrict__ ball, bf16* __restrict__ Wmb) {
  int id = blockIdx.x * 256 + threadIdx.x;
  if (id < 65536)        Wall[id] = (bf16)Wq[id];
  else if (id < 131072)  Wall[id] = (bf16)Wk[id - 65536];
  else if (id < 196608)  Wall[id] = (bf16)Wv[id - 131072];
  else if (id < 262144)  Wmb[id - 196608] = (bf16)Wm[id - 196608];
  else if (id < 262912) {
    int k = id - 262144;
    ball[k] = (k < 256) ? bq[k] : (k < 512) ? bk[k - 256] : bv[k - 512];
  }
}

// ---------------- kernel 1: x[b][c][l] f32 -> xT[b][l][c] bf16 ----------------
__global__ __launch_bounds__(256) void k_tx(const float* __restrict__ x,
                                            bf16* __restrict__ xT) {
  __shared__ float t[32][33];
  const int b = blockIdx.z, c0 = blockIdx.y * 32, l0 = blockIdx.x * 32;
  const int tx = threadIdx.x, ty = threadIdx.y;  // block (32,8)
  #pragma unroll
  for (int i = 0; i < 4; ++i) {
    int c = c0 + ty + 8 * i;
    t[ty + 8 * i][tx] = x[((size_t)b * CH + c) * L + l0 + tx];
  }
  __syncthreads();
  #pragma unroll
  for (int i = 0; i < 4; ++i) {
    int l = l0 + ty + 8 * i;
    xT[((size_t)b * L + l) * CH + c0 + tx] = (bf16)t[tx][ty + 8 * i];
  }
}

// ---------------- kernel 2: fused QKV projection + L2 norm ----------------
// grid (16 l-tiles, 12 strips, B). strip 0-3: Q head, 4-7: K head, 8-11: V head.
// wave: M=64 (strip) x N=64 (l), K=256.
__global__ __launch_bounds__(256) void k_proj(
    const bf16* __restrict__ Wall, const float* __restrict__ ball,
    const bf16* __restrict__ xT, bf16* __restrict__ Qt,
    bf16* __restrict__ Kt, bf16* __restrict__ Vd) {
  const int b = blockIdx.z, strip = blockIdx.y, lt = blockIdx.x;
  const int w = threadIdx.x >> 6;
  const int lane = threadIdx.x & 63;
  const int lo = lane & 15, g = lane >> 4;
  const int l0 = lt * 256 + w * 64;

  const bf16* wbase = Wall + (size_t)strip * 64 * CH;
  const bf16* xbase = xT + (size_t)b * L * CH;

  f32x4 acc[4][4];
  #pragma unroll
  for (int m = 0; m < 4; ++m)
    #pragma unroll
    for (int n = 0; n < 4; ++n) acc[m][n] = (f32x4){0.f, 0.f, 0.f, 0.f};

  #pragma unroll
  for (int kc = 0; kc < 8; ++kc) {
    bf16x8 aw[4], bx[4];
    #pragma unroll
    for (int m = 0; m < 4; ++m)
      aw[m] = *(const bf16x8*)(wbase + (size_t)(16 * m + lo) * CH + kc * 32 + g * 8);
    #pragma unroll
    for (int n = 0; n < 4; ++n)
      bx[n] = *(const bf16x8*)(xbase + (size_t)(l0 + 16 * n + lo) * CH + kc * 32 + g * 8);
    #pragma unroll
    for (int m = 0; m < 4; ++m)
      #pragma unroll
      for (int n = 0; n < 4; ++n) acc[m][n] = MFMA16(aw[m], bx[n], acc[m][n]);
  }

  // bias (before norm, as in reference)
  #pragma unroll
  for (int m = 0; m < 4; ++m)
    #pragma unroll
    for (int r = 0; r < 4; ++r) {
      float bias = ball[strip * 64 + 16 * m + 4 * g + r];
      #pragma unroll
      for (int n = 0; n < 4; ++n) acc[m][n][r] += bias;
    }

  if (strip < 8) {
    // L2-normalize each column l over its 64 d's
    #pragma unroll
    for (int n = 0; n < 4; ++n) {
      float ss = 0.f;
      #pragma unroll
      for (int m = 0; m < 4; ++m)
        #pragma unroll
        for (int r = 0; r < 4; ++r) ss += acc[m][n][r] * acc[m][n][r];
      ss += __shfl_xor(ss, 16);
      ss += __shfl_xor(ss, 32);
      float sc = 1.f / fmaxf(sqrtf(ss), 1e-6f);
      #pragma unroll
      for (int m = 0; m < 4; ++m)
        #pragma unroll
        for (int r = 0; r < 4; ++r) acc[m][n][r] *= sc;
    }
    bf16* dst = (strip < 4) ? Qt : Kt;
    const int h = strip & 3;
    #pragma unroll
    for (int n = 0; n < 4; ++n) {
      const int l = l0 + 16 * n + lo;
      #pragma unroll
      for (int m = 0; m < 4; ++m) {
        size_t base = ((size_t)(b * NH + h) * L + l) * 64 + 16 * m + 4 * g;
        bf16x2 v01, v23;
        v01[0] = (bf16)acc[m][n][0]; v01[1] = (bf16)acc[m][n][1];
        v23[0] = (bf16)acc[m][n][2]; v23[1] = (bf16)acc[m][n][3];
        *(bf16x2*)(dst + base)     = v01;
        *(bf16x2*)(dst + base + 2) = v23;
      }
    }
  } else {
    const int h = strip - 8;
    #pragma unroll
    for (int m = 0; m < 4; ++m)
      #pragma unroll
      for (int r = 0; r < 4; ++r) {
        const int d = 16 * m + 4 * g + r;
        #pragma unroll
        for (int n = 0; n < 4; ++n) {
          const int l = l0 + 16 * n + lo;
          Vd[((size_t)(b * NH + h) * 64 + d) * L + l] = (bf16)acc[m][n][r];
        }
      }
  }
}

// ---------------- kernel 3: attention (no-max streaming softmax) ----------------
// grid (64 q-tiles, 8 bh), 4 waves x 16 q-rows each.
__global__ __launch_bounds__(256) void k_attn(
    const bf16* __restrict__ Qt, const bf16* __restrict__ Kt,
    const bf16* __restrict__ Vd, bf16* __restrict__ Rt) {
  const int bh = blockIdx.y;  // b*4+h
  const int qt = blockIdx.x;
  const int w = threadIdx.x >> 6;
  const int lane = threadIdx.x & 63;
  const int lo = lane & 15, g = lane >> 4;
  const int i0 = qt * 64 + w * 16;

  __shared__ __align__(16) bf16 pbuf[4][16 * 64];  // per-wave P tile, XOR-swizzled

  const bf16* qbase = Qt + ((size_t)bh * L + i0 + lo) * 64;
  bf16x8 aq0 = *(const bf16x8*)(qbase + g * 8);
  bf16x8 aq1 = *(const bf16x8*)(qbase + 32 + g * 8);

  f32x4 racc[4];
  float denom[4] = {0.f, 0.f, 0.f, 0.f};
  #pragma unroll
  for (int t = 0; t < 4; ++t) racc[t] = (f32x4){0.f, 0.f, 0.f, 0.f};

  const bf16* kb = Kt + (size_t)bh * L * 64;
  const bf16* vb = Vd + (size_t)bh * 64 * L;

  for (int j0 = 0; j0 < L; j0 += 64) {
    // S = Q K^T (16 x 64)
    f32x4 s[4];
    #pragma unroll
    for (int t = 0; t < 4; ++t) {
      const bf16* kr = kb + (size_t)(j0 + 16 * t + lo) * 64;
      bf16x8 b0 = *(const bf16x8*)(kr + g * 8);
      bf16x8 b1 = *(const bf16x8*)(kr + 32 + g * 8);
      f32x4 z = (f32x4){0.f, 0.f, 0.f, 0.f};
      z = MFMA16(aq0, b0, z);
      z = MFMA16(aq1, b1, z);
      s[t] = z;
    }
    // P = exp(S): scores in [-1,1] -> no max subtraction needed
    #pragma unroll
    for (int t = 0; t < 4; ++t) {
      #pragma unroll
      for (int r = 0; r < 4; ++r) {
        float p = __expf(s[t][r]);
        denom[r] += p;
        int row = 4 * g + r;
        int col = 16 * t + lo;
        pbuf[w][row * 64 + (col ^ ((row & 7) << 3))] = (bf16)p;
      }
    }
    // read P as A-fragments (swizzled b128 reads)
    bf16x8 pa0 = *(const bf16x8*)(&pbuf[w][lo * 64 + ((g * 8)      ^ ((lo & 7) << 3))]);
    bf16x8 pa1 = *(const bf16x8*)(&pbuf[w][lo * 64 + ((g * 8 + 32) ^ ((lo & 7) << 3))]);
    // R += P V^T
    #pragma unroll
    for (int t = 0; t < 4; ++t) {
      const bf16* vr = vb + (size_t)(16 * t + lo) * L + j0;
      bf16x8 b0 = *(const bf16x8*)(vr + g * 8);
      bf16x8 b1 = *(const bf16x8*)(vr + 32 + g * 8);
      racc[t] = MFMA16(pa0, b0, racc[t]);
      racc[t] = MFMA16(pa1, b1, racc[t]);
    }
  }

  // reduce denominators across the 16 lanes of each row-group
  #pragma unroll
  for (int r = 0; r < 4; ++r) {
    float d = denom[r];
    d += __shfl_xor(d, 1);
    d += __shfl_xor(d, 2);
    d += __shfl_xor(d, 4);
    d += __shfl_xor(d, 8);
    denom[r] = 1.0f / d;
  }

  const int b = bh >> 2, h = bh & 3;
  #pragma unroll
  for (int t = 0; t < 4; ++t)
    #pragma unroll
    for (int r = 0; r < 4; ++r) {
      int i = i0 + 4 * g + r;
      int c = h * 64 + 16 * t + lo;
      Rt[((size_t)b * L + i) * CH + c] = (bf16)(racc[t][r] * denom[r]);
    }
}

// ---------------- kernel 4: output projection + bias + residual ----------------
// grid (64 l-tiles, B), wave: M=64(o) x N=64(l), K=256.
__global__ __launch_bounds__(256) void k_out(
    const bf16* __restrict__ Wmb, const bf16* __restrict__ Rt,
    const float* __restrict__ x, const float* __restrict__ bm,
    float* __restrict__ out) {
  const int b = blockIdx.y, lt = blockIdx.x;
  const int w = threadIdx.x >> 6;
  const int lane = threadIdx.x & 63;
  const int lo = lane & 15, g = lane >> 4;
  const int o0 = w * 64, l0 = lt * 64;

  f32x4 acc[4][4];
  #pragma unroll
  for (int m = 0; m < 4; ++m)
    #pragma unroll
    for (int n = 0; n < 4; ++n) acc[m][n] = (f32x4){0.f, 0.f, 0.f, 0.f};

  #pragma unroll
  for (int kc = 0; kc < 8; ++kc) {
    bf16x8 aw[4], bx[4];
    #pragma unroll
    for (int m = 0; m < 4; ++m)
      aw[m] = *(const bf16x8*)(Wmb + (size_t)(o0 + 16 * m + lo) * CH + kc * 32 + g * 8);
    #pragma unroll
    for (int n = 0; n < 4; ++n)
      bx[n] = *(const bf16x8*)(Rt + ((size_t)b * L + l0 + 16 * n + lo) * CH + kc * 32 + g * 8);
    #pragma unroll
    for (int m = 0; m < 4; ++m)
      #pragma unroll
      for (int n = 0; n < 4; ++n) acc[m][n] = MFMA16(aw[m], bx[n], acc[m][n]);
  }

  #pragma unroll
  for (int m = 0; m < 4; ++m)
    #pragma unroll
    for (int r = 0; r < 4; ++r) {
      const int o = o0 + 16 * m + 4 * g + r;
      const float bias = bm[o];
      #pragma unroll
      for (int n = 0; n < 4; ++n) {
        const int l = l0 + 16 * n + lo;
        size_t idx = ((size_t)b * CH + o) * (size_t)L + l;
        out[idx] = acc[m][n][r] + bias + x[idx];
      }
    }
}

// ---------------- launcher ----------------
extern "C" void kernel_launch(void* const* d_in, const int* in_sizes, int n_in,
                              void* d_out, int out_size, void* d_ws, size_t ws_size,
                              hipStream_t stream) {
  const float* x  = (const float*)d_in[0];
  const float* Wq = (const float*)d_in[1];
  const float* bq = (const float*)d_in[2];
  const float* Wk = (const float*)d_in[3];
  const float* bk = (const float*)d_in[4];
  const float* Wv = (const float*)d_in[5];
  const float* bv = (const float*)d_in[6];
  const float* Wm = (const float*)d_in[7];
  const float* bm = (const float*)d_in[8];
  float* out = (float*)d_out;

  char* ws = (char*)d_ws;
  bf16*  Wall = (bf16*)(ws + OFF_WALL);
  bf16*  Wmb  = (bf16*)(ws + OFF_WMB);
  float* ball = (float*)(ws + OFF_BALL);
  bf16*  xT   = (bf16*)(ws + OFF_XT);
  bf16*  Qt   = (bf16*)(ws + OFF_QT);
  bf16*  Kt   = (bf16*)(ws + OFF_KT);
  bf16*  Vd   = (bf16*)(ws + OFF_VD);
  bf16*  Rt   = (bf16*)(ws + OFF_RT);

  k_wcvt<<<1027, 256, 0, stream>>>(Wq, Wk, Wv, bq, bk, bv, Wm, Wall, ball, Wmb);
  k_tx<<<dim3(L / 32, CH / 32, 2), dim3(32, 8), 0, stream>>>(x, xT);
  k_proj<<<dim3(16, 12, 2), 256, 0, stream>>>(Wall, ball, xT, Qt, Kt, Vd);
  k_attn<<<dim3(64, 8), 256, 0, stream>>>(Qt, Kt, Vd, Rt);
  k_out<<<dim3(64, 2), 256, 0, stream>>>(Wmb, Rt, x, bm, out);
}

// Round 2
// 179.163 us; speedup vs baseline: 1.5739x; 1.5739x over previous
//
#include <hip/hip_runtime.h>
#include <hip/hip_bf16.h>
#include <cstdint>
#include <cstddef>

typedef __bf16 bf16;
typedef bf16 bf16x8 __attribute__((ext_vector_type(8)));
typedef bf16 bf16x4 __attribute__((ext_vector_type(4)));
typedef bf16 bf16x2 __attribute__((ext_vector_type(2)));
typedef float f32x4 __attribute__((ext_vector_type(4)));

#define MFMA16(A, B, Cc) __builtin_amdgcn_mfma_f32_16x16x32_bf16((A), (B), (Cc), 0, 0, 0)

static constexpr int L   = 4096;  // H*W
static constexpr int CH  = 256;   // channels
static constexpr int NH  = 4;     // heads

// workspace layout (bytes), all 16B aligned
static constexpr size_t OFF_WALL = 0;         // 768*256 bf16
static constexpr size_t OFF_WMB  = 393216;    // 256*256 bf16
static constexpr size_t OFF_BALL = 524288;    // 768 f32 (+pad)
static constexpr size_t OFF_XT   = 528384;    // [B][L][C] bf16       (4 MB)
static constexpr size_t OFF_QT   = 4722688;   // [B][H][L][64] bf16   (4 MB)  -- Rt aliases this in split path
static constexpr size_t OFF_KT   = 8916992;   // [B][H][L][64] bf16   (4 MB)
static constexpr size_t OFF_VD   = 13111296;  // [B][H][64][L] bf16   (4 MB)
static constexpr size_t OFF_RP0  = 17305600;  // partial R js=0, bf16 (4 MB)  -- Rt lives here in no-split path
static constexpr size_t OFF_RP1  = 21499904;  // partial R js=1, bf16 (4 MB)
static constexpr size_t OFF_DP0  = 25694208;  // partial denom js=0, f32 (128 KB)
static constexpr size_t OFF_DP1  = 25825280;  // partial denom js=1, f32 (128 KB)
static constexpr size_t NEED_SPLIT = 25956352;

// ---------------- kernel 0: weight/bias conversion ----------------
__global__ __launch_bounds__(256) void k_wcvt(
    const float* __restrict__ Wq, const float* __restrict__ Wk,
    const float* __restrict__ Wv, const float* __restrict__ bq,
    const float* __restrict__ bk, const float* __restrict__ bv,
    const float* __restrict__ Wm, bf16* __restrict__ Wall,
    float* __restrict__ ball, bf16* __restrict__ Wmb) {
  int id = blockIdx.x * 256 + threadIdx.x;
  if (id < 65536)        Wall[id] = (bf16)Wq[id];
  else if (id < 131072)  Wall[id] = (bf16)Wk[id - 65536];
  else if (id < 196608)  Wall[id] = (bf16)Wv[id - 131072];
  else if (id < 262144)  Wmb[id - 196608] = (bf16)Wm[id - 196608];
  else if (id < 262912) {
    int k = id - 262144;
    ball[k] = (k < 256) ? bq[k] : (k < 512) ? bk[k - 256] : bv[k - 512];
  }
}

// ---------------- kernel 1: x[b][c][l] f32 -> xT[b][l][c] bf16 ----------------
__global__ __launch_bounds__(256) void k_tx(const float* __restrict__ x,
                                            bf16* __restrict__ xT) {
  __shared__ float t[32][33];
  const int b = blockIdx.z, c0 = blockIdx.y * 32, l0 = blockIdx.x * 32;
  const int tx = threadIdx.x, ty = threadIdx.y;  // block (32,8)
  #pragma unroll
  for (int i = 0; i < 4; ++i) {
    int c = c0 + ty + 8 * i;
    t[ty + 8 * i][tx] = x[((size_t)b * CH + c) * L + l0 + tx];
  }
  __syncthreads();
  #pragma unroll
  for (int i = 0; i < 4; ++i) {
    int l = l0 + ty + 8 * i;
    xT[((size_t)b * L + l) * CH + c0 + tx] = (bf16)t[tx][ty + 8 * i];
  }
}

// ---------------- kernel 2: fused QKV projection + L2 norm ----------------
__global__ __launch_bounds__(256) void k_proj(
    const bf16* __restrict__ Wall, const float* __restrict__ ball,
    const bf16* __restrict__ xT, bf16* __restrict__ Qt,
    bf16* __restrict__ Kt, bf16* __restrict__ Vd) {
  const int b = blockIdx.z, strip = blockIdx.y, lt = blockIdx.x;
  const int w = threadIdx.x >> 6;
  const int lane = threadIdx.x & 63;
  const int lo = lane & 15, g = lane >> 4;
  const int l0 = lt * 256 + w * 64;

  const bf16* wbase = Wall + (size_t)strip * 64 * CH;
  const bf16* xbase = xT + (size_t)b * L * CH;

  f32x4 acc[4][4];
  #pragma unroll
  for (int m = 0; m < 4; ++m)
    #pragma unroll
    for (int n = 0; n < 4; ++n) acc[m][n] = (f32x4){0.f, 0.f, 0.f, 0.f};

  #pragma unroll
  for (int kc = 0; kc < 8; ++kc) {
    bf16x8 aw[4], bx[4];
    #pragma unroll
    for (int m = 0; m < 4; ++m)
      aw[m] = *(const bf16x8*)(wbase + (size_t)(16 * m + lo) * CH + kc * 32 + g * 8);
    #pragma unroll
    for (int n = 0; n < 4; ++n)
      bx[n] = *(const bf16x8*)(xbase + (size_t)(l0 + 16 * n + lo) * CH + kc * 32 + g * 8);
    #pragma unroll
    for (int m = 0; m < 4; ++m)
      #pragma unroll
      for (int n = 0; n < 4; ++n) acc[m][n] = MFMA16(aw[m], bx[n], acc[m][n]);
  }

  #pragma unroll
  for (int m = 0; m < 4; ++m)
    #pragma unroll
    for (int r = 0; r < 4; ++r) {
      float bias = ball[strip * 64 + 16 * m + 4 * g + r];
      #pragma unroll
      for (int n = 0; n < 4; ++n) acc[m][n][r] += bias;
    }

  if (strip < 8) {
    #pragma unroll
    for (int n = 0; n < 4; ++n) {
      float ss = 0.f;
      #pragma unroll
      for (int m = 0; m < 4; ++m)
        #pragma unroll
        for (int r = 0; r < 4; ++r) ss += acc[m][n][r] * acc[m][n][r];
      ss += __shfl_xor(ss, 16);
      ss += __shfl_xor(ss, 32);
      float sc = 1.f / fmaxf(sqrtf(ss), 1e-6f);
      #pragma unroll
      for (int m = 0; m < 4; ++m)
        #pragma unroll
        for (int r = 0; r < 4; ++r) acc[m][n][r] *= sc;
    }
    bf16* dst = (strip < 4) ? Qt : Kt;
    const int h = strip & 3;
    #pragma unroll
    for (int n = 0; n < 4; ++n) {
      const int l = l0 + 16 * n + lo;
      #pragma unroll
      for (int m = 0; m < 4; ++m) {
        size_t base = ((size_t)(b * NH + h) * L + l) * 64 + 16 * m + 4 * g;
        bf16x2 v01, v23;
        v01[0] = (bf16)acc[m][n][0]; v01[1] = (bf16)acc[m][n][1];
        v23[0] = (bf16)acc[m][n][2]; v23[1] = (bf16)acc[m][n][3];
        *(bf16x2*)(dst + base)     = v01;
        *(bf16x2*)(dst + base + 2) = v23;
      }
    }
  } else {
    const int h = strip - 8;
    #pragma unroll
    for (int m = 0; m < 4; ++m)
      #pragma unroll
      for (int r = 0; r < 4; ++r) {
        const int d = 16 * m + 4 * g + r;
        #pragma unroll
        for (int n = 0; n < 4; ++n) {
          const int l = l0 + 16 * n + lo;
          Vd[((size_t)(b * NH + h) * 64 + d) * L + l] = (bf16)acc[m][n][r];
        }
      }
  }
}

// ---------------- kernel 3: attention ----------------
// Swapped QK (A=K rows=j, B=Q cols=q): C gives 4 consecutive j per lane ->
// packed b64 P-writes into XOR-swizzled per-wave LDS. K frags reg-double-
// buffered (ping-pong, static idx). 32 q/wave, 4 waves = 128 q/block.
// SPLIT: j-range halved across 2 blocks; partials (bf16 R, f32 denom).
// Block id: id%8 == bh -> per-head XCD affinity (K/V L2-resident).

#define ATTN_BODY(CUR, NXT, J0, JN)                                            \
  {                                                                            \
    _Pragma("unroll") for (int t = 0; t < 4; ++t)                              \
      _Pragma("unroll") for (int s = 0; s < 2; ++s)                            \
        NXT[t][s] = *(const bf16x8*)(kptr + (size_t)((JN) + 16 * t + lo) * 64 + 32 * s + 8 * g); \
    bf16x8 vf[4][2];                                                           \
    _Pragma("unroll") for (int n = 0; n < 4; ++n)                              \
      _Pragma("unroll") for (int s = 0; s < 2; ++s)                            \
        vf[n][s] = *(const bf16x8*)(vptr + (size_t)(16 * n + lo) * L + (J0) + 32 * s + 8 * g); \
    _Pragma("unroll") for (int t = 0; t < 4; ++t) {                            \
      _Pragma("unroll") for (int m = 0; m < 2; ++m) {                          \
        f32x4 z = (f32x4){0.f, 0.f, 0.f, 0.f};                                 \
        z = MFMA16(CUR[t][0], qf[m][0], z);                                    \
        z = MFMA16(CUR[t][1], qf[m][1], z);                                    \
        float p0 = __expf(z[0]), p1 = __expf(z[1]);                            \
        float p2 = __expf(z[2]), p3 = __expf(z[3]);                            \
        den[m] += (p0 + p1) + (p2 + p3);                                       \
        bf16x4 pk;                                                             \
        pk[0] = (bf16)p0; pk[1] = (bf16)p1; pk[2] = (bf16)p2; pk[3] = (bf16)p3;\
        const int qrow = 16 * m + lo;                                          \
        const int byt = qrow * 128 + ((32 * t + 8 * g) ^ ((qrow & 7) << 4));   \
        *(bf16x4*)(pbw + byt) = pk;                                            \
      }                                                                        \
    }                                                                          \
    bf16x8 pa[2][2];                                                           \
    _Pragma("unroll") for (int m = 0; m < 2; ++m)                              \
      _Pragma("unroll") for (int s = 0; s < 2; ++s) {                          \
        const int qrow = 16 * m + lo;                                          \
        const int byt = qrow * 128 + ((64 * s + 16 * g) ^ ((qrow & 7) << 4));  \
        pa[m][s] = *(const bf16x8*)(pbw + byt);                                \
      }                                                                        \
    _Pragma("unroll") for (int m = 0; m < 2; ++m)                              \
      _Pragma("unroll") for (int n = 0; n < 4; ++n) {                          \
        racc[m][n] = MFMA16(pa[m][0], vf[n][0], racc[m][n]);                   \
        racc[m][n] = MFMA16(pa[m][1], vf[n][1], racc[m][n]);                   \
      }                                                                        \
  }

template <bool SPLIT>
__global__ __launch_bounds__(256) void k_attn(
    const bf16* __restrict__ Qt, const bf16* __restrict__ Kt,
    const bf16* __restrict__ Vd, bf16* __restrict__ Rp0,
    bf16* __restrict__ Rp1, float* __restrict__ Dp0,
    float* __restrict__ Dp1, bf16* __restrict__ Rt) {
  const int id = blockIdx.x;
  const int bh = id & 7;
  const int tmp = id >> 3;
  const int js = SPLIT ? (tmp & 1) : 0;
  const int qt = SPLIT ? (tmp >> 1) : tmp;
  const int w = threadIdx.x >> 6;
  const int lane = threadIdx.x & 63;
  const int lo = lane & 15, g = lane >> 4;
  const int i0 = qt * 128 + w * 32;

  __shared__ __align__(16) char pb_raw[4 * 32 * 128];  // P: per-wave 32q x 64j bf16
  __shared__ float dsm[4][32];
  char* pbw = pb_raw + w * 32 * 128;

  const bf16* qb   = Qt + ((size_t)bh * L + i0) * 64;
  const bf16* kptr = Kt + (size_t)bh * L * 64;
  const bf16* vptr = Vd + (size_t)bh * 64 * L;

  bf16x8 qf[2][2];
  #pragma unroll
  for (int m = 0; m < 2; ++m)
    #pragma unroll
    for (int s = 0; s < 2; ++s)
      qf[m][s] = *(const bf16x8*)(qb + (size_t)(16 * m + lo) * 64 + 32 * s + 8 * g);

  f32x4 racc[2][4];
  #pragma unroll
  for (int m = 0; m < 2; ++m)
    #pragma unroll
    for (int n = 0; n < 4; ++n) racc[m][n] = (f32x4){0.f, 0.f, 0.f, 0.f};
  float den[2] = {0.f, 0.f};

  const int jbeg = js * (L / 2);
  const int nit = SPLIT ? (L / 128) : (L / 64);

  bf16x8 kfA[4][2], kfB[4][2];
  #pragma unroll
  for (int t = 0; t < 4; ++t)
    #pragma unroll
    for (int s = 0; s < 2; ++s)
      kfA[t][s] = *(const bf16x8*)(kptr + (size_t)(jbeg + 16 * t + lo) * 64 + 32 * s + 8 * g);

  for (int it = 0; it < nit; it += 2) {
    const int j0 = jbeg + it * 64;
    const int j1 = j0 + 64;
    const int j2 = (it + 2 < nit) ? j0 + 128 : jbeg;  // dummy reload on last
    ATTN_BODY(kfA, kfB, j0, j1)
    ATTN_BODY(kfB, kfA, j1, j2)
  }

  // full denominator per q = 16m+lo (sum the 4 g-groups)
  #pragma unroll
  for (int m = 0; m < 2; ++m) {
    den[m] += __shfl_xor(den[m], 16);
    den[m] += __shfl_xor(den[m], 32);
  }

  if (SPLIT) {
    bf16* rp = js ? Rp1 : Rp0;
    float* dp = js ? Dp1 : Dp0;
    if (lane < 16) {
      #pragma unroll
      for (int m = 0; m < 2; ++m)
        dp[(size_t)bh * L + i0 + 16 * m + lo] = den[m];
    }
    #pragma unroll
    for (int m = 0; m < 2; ++m)
      #pragma unroll
      for (int n = 0; n < 4; ++n)
        #pragma unroll
        for (int r = 0; r < 4; ++r) {
          const int q = 16 * m + 4 * g + r;
          rp[((size_t)bh * L + i0 + q) * 64 + 16 * n + lo] = (bf16)racc[m][n][r];
        }
  } else {
    if (lane < 16) {
      dsm[w][lo] = den[0];
      dsm[w][16 + lo] = den[1];
    }
    const int b = bh >> 2, h = bh & 3;
    #pragma unroll
    for (int m = 0; m < 2; ++m)
      #pragma unroll
      for (int r = 0; r < 4; ++r) {
        const int q = 16 * m + 4 * g + r;
        const float inv = 1.0f / dsm[w][q];
        #pragma unroll
        for (int n = 0; n < 4; ++n)
          Rt[((size_t)b * L + i0 + q) * CH + h * 64 + 16 * n + lo] =
              (bf16)(racc[m][n][r] * inv);
      }
  }
}

// ---------------- kernel 3b: combine partials -> Rt ----------------
__global__ __launch_bounds__(256) void k_comb(
    const bf16* __restrict__ Rp0, const bf16* __restrict__ Rp1,
    const float* __restrict__ Dp0, const float* __restrict__ Dp1,
    bf16* __restrict__ Rt) {
  const int tid = blockIdx.x * 256 + threadIdx.x;  // 262144 threads
  const int e8 = tid * 8;
  const int d8 = e8 & 63;
  const int l = (e8 >> 6) & (L - 1);
  const int bh = e8 >> 18;
  bf16x8 a = *(const bf16x8*)(Rp0 + e8);
  bf16x8 c = *(const bf16x8*)(Rp1 + e8);
  const float inv = 1.0f / (Dp0[(size_t)bh * L + l] + Dp1[(size_t)bh * L + l]);
  bf16x8 o;
  #pragma unroll
  for (int e = 0; e < 8; ++e) o[e] = (bf16)(((float)a[e] + (float)c[e]) * inv);
  *(bf16x8*)(Rt + ((size_t)(bh >> 2) * L + l) * CH + (bh & 3) * 64 + d8) = o;
}

// ---------------- kernel 4: output projection + bias + residual ----------------
__global__ __launch_bounds__(256) void k_out(
    const bf16* __restrict__ Wmb, const bf16* __restrict__ Rt,
    const float* __restrict__ x, const float* __restrict__ bm,
    float* __restrict__ out) {
  const int b = blockIdx.y, lt = blockIdx.x;
  const int w = threadIdx.x >> 6;
  const int lane = threadIdx.x & 63;
  const int lo = lane & 15, g = lane >> 4;
  const int o0 = w * 64, l0 = lt * 64;

  f32x4 acc[4][4];
  #pragma unroll
  for (int m = 0; m < 4; ++m)
    #pragma unroll
    for (int n = 0; n < 4; ++n) acc[m][n] = (f32x4){0.f, 0.f, 0.f, 0.f};

  #pragma unroll
  for (int kc = 0; kc < 8; ++kc) {
    bf16x8 aw[4], bx[4];
    #pragma unroll
    for (int m = 0; m < 4; ++m)
      aw[m] = *(const bf16x8*)(Wmb + (size_t)(o0 + 16 * m + lo) * CH + kc * 32 + g * 8);
    #pragma unroll
    for (int n = 0; n < 4; ++n)
      bx[n] = *(const bf16x8*)(Rt + ((size_t)b * L + l0 + 16 * n + lo) * CH + kc * 32 + g * 8);
    #pragma unroll
    for (int m = 0; m < 4; ++m)
      #pragma unroll
      for (int n = 0; n < 4; ++n) acc[m][n] = MFMA16(aw[m], bx[n], acc[m][n]);
  }

  #pragma unroll
  for (int m = 0; m < 4; ++m)
    #pragma unroll
    for (int r = 0; r < 4; ++r) {
      const int o = o0 + 16 * m + 4 * g + r;
      const float bias = bm[o];
      #pragma unroll
      for (int n = 0; n < 4; ++n) {
        const int l = l0 + 16 * n + lo;
        size_t idx = ((size_t)b * CH + o) * (size_t)L + l;
        out[idx] = acc[m][n][r] + bias + x[idx];
      }
    }
}

// ---------------- launcher ----------------
extern "C" void kernel_launch(void* const* d_in, const int* in_sizes, int n_in,
                              void* d_out, int out_size, void* d_ws, size_t ws_size,
                              hipStream_t stream) {
  const float* x  = (const float*)d_in[0];
  const float* Wq = (const float*)d_in[1];
  const float* bq = (const float*)d_in[2];
  const float* Wk = (const float*)d_in[3];
  const float* bk = (const float*)d_in[4];
  const float* Wv = (const float*)d_in[5];
  const float* bv = (const float*)d_in[6];
  const float* Wm = (const float*)d_in[7];
  const float* bm = (const float*)d_in[8];
  float* out = (float*)d_out;

  char* ws = (char*)d_ws;
  bf16*  Wall = (bf16*)(ws + OFF_WALL);
  bf16*  Wmb  = (bf16*)(ws + OFF_WMB);
  float* ball = (float*)(ws + OFF_BALL);
  bf16*  xT   = (bf16*)(ws + OFF_XT);
  bf16*  Qt   = (bf16*)(ws + OFF_QT);
  bf16*  Kt   = (bf16*)(ws + OFF_KT);
  bf16*  Vd   = (bf16*)(ws + OFF_VD);
  bf16*  Rp0  = (bf16*)(ws + OFF_RP0);
  bf16*  Rp1  = (bf16*)(ws + OFF_RP1);
  float* Dp0  = (float*)(ws + OFF_DP0);
  float* Dp1  = (float*)(ws + OFF_DP1);

  const bool split = ws_size >= NEED_SPLIT;
  // split: Rt aliases Qt (dead after k_attn; k_comb runs after). no-split: Rt at RP0.
  bf16* Rt = split ? (bf16*)(ws + OFF_QT) : (bf16*)(ws + OFF_RP0);

  k_wcvt<<<1027, 256, 0, stream>>>(Wq, Wk, Wv, bq, bk, bv, Wm, Wall, ball, Wmb);
  k_tx<<<dim3(L / 32, CH / 32, 2), dim3(32, 8), 0, stream>>>(x, xT);
  k_proj<<<dim3(16, 12, 2), 256, 0, stream>>>(Wall, ball, xT, Qt, Kt, Vd);
  if (split) {
    k_attn<true><<<512, 256, 0, stream>>>(Qt, Kt, Vd, Rp0, Rp1, Dp0, Dp1, nullptr);
    k_comb<<<1024, 256, 0, stream>>>(Rp0, Rp1, Dp0, Dp1, Rt);
  } else {
    k_attn<false><<<256, 256, 0, stream>>>(Qt, Kt, Vd, nullptr, nullptr, nullptr, nullptr, Rt);
  }
  k_out<<<dim3(64, 2), 256, 0, stream>>>(Wmb, Rt, x, bm, out);
}

// Round 3
// 107.033 us; speedup vs baseline: 2.6345x; 1.6739x over previous
//
#include <hip/hip_runtime.h>
#include <hip/hip_bf16.h>
#include <cstdint>
#include <cstddef>

typedef __bf16 bf16;
typedef bf16 bf16x8 __attribute__((ext_vector_type(8)));
typedef bf16 bf16x4 __attribute__((ext_vector_type(4)));
typedef bf16 bf16x2 __attribute__((ext_vector_type(2)));
typedef float f32x4 __attribute__((ext_vector_type(4)));

#define MFMA16(A, B, Cc) __builtin_amdgcn_mfma_f32_16x16x32_bf16((A), (B), (Cc), 0, 0, 0)
#define GLD16(g, l)                                                          \
  __builtin_amdgcn_global_load_lds(                                          \
      (const __attribute__((address_space(1))) void*)(g),                    \
      (__attribute__((address_space(3))) void*)(l), 16, 0, 0)

static constexpr int L   = 4096;  // H*W
static constexpr int CH  = 256;   // channels
static constexpr int NH  = 4;     // heads

// workspace layout (bytes), all 16B aligned
static constexpr size_t OFF_WALL = 0;         // 768*256 bf16
static constexpr size_t OFF_WMB  = 393216;    // 256*256 bf16
static constexpr size_t OFF_BALL = 524288;    // 768 f32 (+pad)
static constexpr size_t OFF_XT   = 528384;    // [B][L][C] bf16 (4MB) -- Rp0 aliases after k_proj
static constexpr size_t OFF_QT   = 4722688;   // [B][H][L][64] bf16 (4MB) -- Rt aliases after k_attn
static constexpr size_t OFF_KT   = 8916992;   // [B][H][L][64] bf16 (4MB)
static constexpr size_t OFF_VD   = 13111296;  // [B][H][64][L] bf16 (4MB)
static constexpr size_t OFF_RP1  = 17305600;  // partial R js=1 (4MB)
static constexpr size_t OFF_RP2  = 21499904;  // partial R js=2 (4MB)
static constexpr size_t OFF_RP3  = 25694208;  // partial R js=3 (4MB)
static constexpr size_t OFF_DP4  = 29888512;  // 4 x [8][4096] f32 denoms (512KB)
static constexpr size_t OFF_DP2  = 21499904;  // JS=2: denoms after RP1
static constexpr size_t NEED4    = 30412800;
// JS=2 needs 21762048 -- guaranteed (R1 ran split path at 25956352)

// ---------------- kernel 0: weight/bias conversion ----------------
__global__ __launch_bounds__(256) void k_wcvt(
    const float* __restrict__ Wq, const float* __restrict__ Wk,
    const float* __restrict__ Wv, const float* __restrict__ bq,
    const float* __restrict__ bk, const float* __restrict__ bv,
    const float* __restrict__ Wm, bf16* __restrict__ Wall,
    float* __restrict__ ball, bf16* __restrict__ Wmb) {
  int id = blockIdx.x * 256 + threadIdx.x;
  if (id < 65536)        Wall[id] = (bf16)Wq[id];
  else if (id < 131072)  Wall[id] = (bf16)Wk[id - 65536];
  else if (id < 196608)  Wall[id] = (bf16)Wv[id - 131072];
  else if (id < 262144)  Wmb[id - 196608] = (bf16)Wm[id - 196608];
  else if (id < 262912) {
    int k = id - 262144;
    ball[k] = (k < 256) ? bq[k] : (k < 512) ? bk[k - 256] : bv[k - 512];
  }
}

// ---------------- kernel 1: x[b][c][l] f32 -> xT[b][l][c] bf16 ----------------
__global__ __launch_bounds__(256) void k_tx(const float* __restrict__ x,
                                            bf16* __restrict__ xT) {
  __shared__ float t[32][33];
  const int b = blockIdx.z, c0 = blockIdx.y * 32, l0 = blockIdx.x * 32;
  const int tx = threadIdx.x, ty = threadIdx.y;  // block (32,8)
  #pragma unroll
  for (int i = 0; i < 4; ++i) {
    int c = c0 + ty + 8 * i;
    t[ty + 8 * i][tx] = x[((size_t)b * CH + c) * L + l0 + tx];
  }
  __syncthreads();
  #pragma unroll
  for (int i = 0; i < 4; ++i) {
    int l = l0 + ty + 8 * i;
    xT[((size_t)b * L + l) * CH + c0 + tx] = (bf16)t[tx][ty + 8 * i];
  }
}

// ---------------- kernel 2: fused QKV projection + L2 norm ----------------
__global__ __launch_bounds__(256) void k_proj(
    const bf16* __restrict__ Wall, const float* __restrict__ ball,
    const bf16* __restrict__ xT, bf16* __restrict__ Qt,
    bf16* __restrict__ Kt, bf16* __restrict__ Vd) {
  const int b = blockIdx.z, strip = blockIdx.y, lt = blockIdx.x;
  const int w = threadIdx.x >> 6;
  const int lane = threadIdx.x & 63;
  const int lo = lane & 15, g = lane >> 4;
  const int l0 = lt * 256 + w * 64;

  const bf16* wbase = Wall + (size_t)strip * 64 * CH;
  const bf16* xbase = xT + (size_t)b * L * CH;

  f32x4 acc[4][4];
  #pragma unroll
  for (int m = 0; m < 4; ++m)
    #pragma unroll
    for (int n = 0; n < 4; ++n) acc[m][n] = (f32x4){0.f, 0.f, 0.f, 0.f};

  #pragma unroll
  for (int kc = 0; kc < 8; ++kc) {
    bf16x8 aw[4], bx[4];
    #pragma unroll
    for (int m = 0; m < 4; ++m)
      aw[m] = *(const bf16x8*)(wbase + (size_t)(16 * m + lo) * CH + kc * 32 + g * 8);
    #pragma unroll
    for (int n = 0; n < 4; ++n)
      bx[n] = *(const bf16x8*)(xbase + (size_t)(l0 + 16 * n + lo) * CH + kc * 32 + g * 8);
    #pragma unroll
    for (int m = 0; m < 4; ++m)
      #pragma unroll
      for (int n = 0; n < 4; ++n) acc[m][n] = MFMA16(aw[m], bx[n], acc[m][n]);
  }

  #pragma unroll
  for (int m = 0; m < 4; ++m)
    #pragma unroll
    for (int r = 0; r < 4; ++r) {
      float bias = ball[strip * 64 + 16 * m + 4 * g + r];
      #pragma unroll
      for (int n = 0; n < 4; ++n) acc[m][n][r] += bias;
    }

  if (strip < 8) {
    #pragma unroll
    for (int n = 0; n < 4; ++n) {
      float ss = 0.f;
      #pragma unroll
      for (int m = 0; m < 4; ++m)
        #pragma unroll
        for (int r = 0; r < 4; ++r) ss += acc[m][n][r] * acc[m][n][r];
      ss += __shfl_xor(ss, 16);
      ss += __shfl_xor(ss, 32);
      float sc = 1.f / fmaxf(sqrtf(ss), 1e-6f);
      #pragma unroll
      for (int m = 0; m < 4; ++m)
        #pragma unroll
        for (int r = 0; r < 4; ++r) acc[m][n][r] *= sc;
    }
    bf16* dst = (strip < 4) ? Qt : Kt;
    const int h = strip & 3;
    #pragma unroll
    for (int n = 0; n < 4; ++n) {
      const int l = l0 + 16 * n + lo;
      #pragma unroll
      for (int m = 0; m < 4; ++m) {
        size_t base = ((size_t)(b * NH + h) * L + l) * 64 + 16 * m + 4 * g;
        bf16x2 v01, v23;
        v01[0] = (bf16)acc[m][n][0]; v01[1] = (bf16)acc[m][n][1];
        v23[0] = (bf16)acc[m][n][2]; v23[1] = (bf16)acc[m][n][3];
        *(bf16x2*)(dst + base)     = v01;
        *(bf16x2*)(dst + base + 2) = v23;
      }
    }
  } else {
    const int h = strip - 8;
    #pragma unroll
    for (int m = 0; m < 4; ++m)
      #pragma unroll
      for (int r = 0; r < 4; ++r) {
        const int d = 16 * m + 4 * g + r;
        #pragma unroll
        for (int n = 0; n < 4; ++n) {
          const int l = l0 + 16 * n + lo;
          Vd[((size_t)(b * NH + h) * 64 + d) * L + l] = (bf16)acc[m][n][r];
        }
      }
  }
}

// ---------------- kernel 3: attention ----------------
// 4 waves x 64 q = 256 q/block. K/V tiles (64j) LDS-staged via global_load_lds,
// double-buffered, shared by all 4 waves. XOR-swizzle (row&7)<<4: LDS dest is
// linear, global SOURCE pre-swizzled, ds_read_b128 swizzled (rule 21).
// Swapped QK (A=K, B=Q) -> packed b64 P-writes to per-wave swizzled pbuf.
// j split JS ways across blocks; bf16 partials + f32 denom, combined by k_comb.
// blockIdx: id&7 == bh -> per-head XCD affinity.

#define STAGE(bb, j0)                                                          \
  {                                                                            \
    const char* gk0 = kbase + (size_t)((j0) + sr) * 128 + scS;                 \
    const char* gk1 = kbase + (size_t)((j0) + 32 + sr) * 128 + scS;            \
    const char* gv0 = vbase + (size_t)sr * 8192 + (size_t)(j0) * 2 + scS;      \
    const char* gv1 = vbase + (size_t)(32 + sr) * 8192 + (size_t)(j0) * 2 + scS; \
    GLD16(gk0, kbuf[bb] + w * 1024 + lane * 16);                               \
    GLD16(gk1, kbuf[bb] + 4096 + w * 1024 + lane * 16);                        \
    GLD16(gv0, vbuf[bb] + w * 1024 + lane * 16);                               \
    GLD16(gv1, vbuf[bb] + 4096 + w * 1024 + lane * 16);                        \
  }

#define COMPUTE(bb)                                                            \
  {                                                                            \
    const char* kb = kbuf[bb];                                                 \
    const char* vb = vbuf[bb];                                                 \
    _Pragma("unroll") for (int t = 0; t < 4; ++t) {                            \
      bf16x8 kf0 = *(const bf16x8*)(kb + (16 * t + lo) * 128 + ((16 * g) ^ sw)); \
      bf16x8 kf1 = *(const bf16x8*)(kb + (16 * t + lo) * 128 + ((64 + 16 * g) ^ sw)); \
      _Pragma("unroll") for (int m = 0; m < 4; ++m) {                          \
        f32x4 z = (f32x4){0.f, 0.f, 0.f, 0.f};                                 \
        z = MFMA16(kf0, qf[m][0], z);                                          \
        z = MFMA16(kf1, qf[m][1], z);                                          \
        float p0 = __expf(z[0]), p1 = __expf(z[1]);                            \
        float p2 = __expf(z[2]), p3 = __expf(z[3]);                            \
        den[m] += (p0 + p1) + (p2 + p3);                                       \
        bf16x4 pk;                                                             \
        pk[0] = (bf16)p0; pk[1] = (bf16)p1; pk[2] = (bf16)p2; pk[3] = (bf16)p3; \
        *(bf16x4*)(pbw + (16 * m + lo) * 128 + ((32 * t + 8 * g) ^ sw)) = pk;  \
      }                                                                        \
    }                                                                          \
    bf16x8 pa[4][2];                                                           \
    _Pragma("unroll") for (int m = 0; m < 4; ++m)                              \
      _Pragma("unroll") for (int s = 0; s < 2; ++s)                            \
        pa[m][s] = *(const bf16x8*)(pbw + (16 * m + lo) * 128 + ((64 * s + 16 * g) ^ sw)); \
    _Pragma("unroll") for (int n = 0; n < 4; ++n) {                            \
      bf16x8 vf0 = *(const bf16x8*)(vb + (16 * n + lo) * 128 + ((16 * g) ^ sw)); \
      bf16x8 vf1 = *(const bf16x8*)(vb + (16 * n + lo) * 128 + ((64 + 16 * g) ^ sw)); \
      _Pragma("unroll") for (int m = 0; m < 4; ++m) {                          \
        racc[m][n] = MFMA16(pa[m][0], vf0, racc[m][n]);                        \
        racc[m][n] = MFMA16(pa[m][1], vf1, racc[m][n]);                        \
      }                                                                        \
    }                                                                          \
  }

template <int JS>
__global__ __launch_bounds__(256, 2) void k_attn(
    const bf16* __restrict__ Qt, const bf16* __restrict__ Kt,
    const bf16* __restrict__ Vd, bf16* __restrict__ R0,
    bf16* __restrict__ R1, bf16* __restrict__ R2, bf16* __restrict__ R3,
    float* __restrict__ D0, float* __restrict__ D1,
    float* __restrict__ D2, float* __restrict__ D3) {
  const int id = blockIdx.x;
  const int bh = id & 7;
  const int qt = (id >> 3) & 15;
  const int js = id >> 7;
  const int tid = threadIdx.x;
  const int w = tid >> 6;
  const int lane = tid & 63;
  const int lo = lane & 15, g = lane >> 4;
  const int sw = (lo & 7) << 4;
  const int i0 = qt * 256 + w * 64;

  __shared__ __align__(16) char kbuf[2][8192];
  __shared__ __align__(16) char vbuf[2][8192];
  __shared__ __align__(16) char pbuf[4][8192];
  char* pbw = pbuf[w];

  const char* kbase = (const char*)(Kt + (size_t)bh * L * 64);
  const char* vbase = (const char*)(Vd + (size_t)bh * 64 * L);

  // staging: thread covers row sr (of 32-row half), linear dest col sc,
  // inverse-swizzled source col scS
  const int sr = tid >> 3;
  const int sc = (tid & 7) * 16;
  const int scS = sc ^ ((sr & 7) << 4);

  // Q fragments (64 q rows per wave)
  const bf16* qb = Qt + ((size_t)bh * L + i0) * 64;
  bf16x8 qf[4][2];
  #pragma unroll
  for (int m = 0; m < 4; ++m)
    #pragma unroll
    for (int s = 0; s < 2; ++s)
      qf[m][s] = *(const bf16x8*)(qb + (size_t)(16 * m + lo) * 64 + 32 * s + 8 * g);

  f32x4 racc[4][4];
  #pragma unroll
  for (int m = 0; m < 4; ++m)
    #pragma unroll
    for (int n = 0; n < 4; ++n) racc[m][n] = (f32x4){0.f, 0.f, 0.f, 0.f};
  float den[4] = {0.f, 0.f, 0.f, 0.f};

  const int jbeg = js * (L / JS);
  const int nt = (L / JS) / 64;

  STAGE(0, jbeg)
  __syncthreads();
  for (int it = 0; it < nt; ++it) {
    const int bb = it & 1;
    if (it + 1 < nt) STAGE(bb ^ 1, jbeg + (it + 1) * 64)
    COMPUTE(bb)
    __syncthreads();  // drains stage vmcnt + guards buffer reuse
  }

  // full denominator per q (sum 4 g-groups)
  #pragma unroll
  for (int m = 0; m < 4; ++m) {
    den[m] += __shfl_xor(den[m], 16);
    den[m] += __shfl_xor(den[m], 32);
  }

  bf16* rp = (js == 0) ? R0 : (js == 1) ? R1 : (js == 2) ? R2 : R3;
  float* dp = (js == 0) ? D0 : (js == 1) ? D1 : (js == 2) ? D2 : D3;

  if (g == 0) {
    #pragma unroll
    for (int m = 0; m < 4; ++m)
      dp[(size_t)bh * L + i0 + 16 * m + lo] = den[m];
  }
  #pragma unroll
  for (int m = 0; m < 4; ++m)
    #pragma unroll
    for (int n = 0; n < 4; ++n)
      #pragma unroll
      for (int r = 0; r < 4; ++r) {
        const int q = 16 * m + 4 * g + r;
        rp[((size_t)bh * L + i0 + q) * 64 + 16 * n + lo] = (bf16)racc[m][n][r];
      }
}

// ---------------- kernel 3b: combine partials -> Rt ----------------
template <int JS>
__global__ __launch_bounds__(256) void k_comb(
    const bf16* __restrict__ R0, const bf16* __restrict__ R1,
    const bf16* __restrict__ R2, const bf16* __restrict__ R3,
    const float* __restrict__ D0, const float* __restrict__ D1,
    const float* __restrict__ D2, const float* __restrict__ D3,
    bf16* __restrict__ Rt) {
  const int tid = blockIdx.x * 256 + threadIdx.x;  // 262144 threads
  const int e8 = tid * 8;
  const int d8 = e8 & 63;
  const int l = (e8 >> 6) & (L - 1);
  const int bh = e8 >> 18;
  const size_t di = (size_t)bh * L + l;
  float den = D0[di] + D1[di];
  if (JS == 4) den += D2[di] + D3[di];
  const float inv = 1.0f / den;
  bf16x8 a0 = *(const bf16x8*)(R0 + e8);
  bf16x8 a1 = *(const bf16x8*)(R1 + e8);
  bf16x8 o;
  if (JS == 4) {
    bf16x8 a2 = *(const bf16x8*)(R2 + e8);
    bf16x8 a3 = *(const bf16x8*)(R3 + e8);
    #pragma unroll
    for (int e = 0; e < 8; ++e)
      o[e] = (bf16)((((float)a0[e] + (float)a1[e]) + ((float)a2[e] + (float)a3[e])) * inv);
  } else {
    #pragma unroll
    for (int e = 0; e < 8; ++e)
      o[e] = (bf16)(((float)a0[e] + (float)a1[e]) * inv);
  }
  *(bf16x8*)(Rt + ((size_t)(bh >> 2) * L + l) * CH + (bh & 3) * 64 + d8) = o;
}

// ---------------- kernel 4: output projection + bias + residual ----------------
__global__ __launch_bounds__(256) void k_out(
    const bf16* __restrict__ Wmb, const bf16* __restrict__ Rt,
    const float* __restrict__ x, const float* __restrict__ bm,
    float* __restrict__ out) {
  const int b = blockIdx.y, lt = blockIdx.x;
  const int w = threadIdx.x >> 6;
  const int lane = threadIdx.x & 63;
  const int lo = lane & 15, g = lane >> 4;
  const int o0 = w * 64, l0 = lt * 64;

  f32x4 acc[4][4];
  #pragma unroll
  for (int m = 0; m < 4; ++m)
    #pragma unroll
    for (int n = 0; n < 4; ++n) acc[m][n] = (f32x4){0.f, 0.f, 0.f, 0.f};

  #pragma unroll
  for (int kc = 0; kc < 8; ++kc) {
    bf16x8 aw[4], bx[4];
    #pragma unroll
    for (int m = 0; m < 4; ++m)
      aw[m] = *(const bf16x8*)(Wmb + (size_t)(o0 + 16 * m + lo) * CH + kc * 32 + g * 8);
    #pragma unroll
    for (int n = 0; n < 4; ++n)
      bx[n] = *(const bf16x8*)(Rt + ((size_t)b * L + l0 + 16 * n + lo) * CH + kc * 32 + g * 8);
    #pragma unroll
    for (int m = 0; m < 4; ++m)
      #pragma unroll
      for (int n = 0; n < 4; ++n) acc[m][n] = MFMA16(aw[m], bx[n], acc[m][n]);
  }

  #pragma unroll
  for (int m = 0; m < 4; ++m)
    #pragma unroll
    for (int r = 0; r < 4; ++r) {
      const int o = o0 + 16 * m + 4 * g + r;
      const float bias = bm[o];
      #pragma unroll
      for (int n = 0; n < 4; ++n) {
        const int l = l0 + 16 * n + lo;
        size_t idx = ((size_t)b * CH + o) * (size_t)L + l;
        out[idx] = acc[m][n][r] + bias + x[idx];
      }
    }
}

// ---------------- launcher ----------------
extern "C" void kernel_launch(void* const* d_in, const int* in_sizes, int n_in,
                              void* d_out, int out_size, void* d_ws, size_t ws_size,
                              hipStream_t stream) {
  const float* x  = (const float*)d_in[0];
  const float* Wq = (const float*)d_in[1];
  const float* bq = (const float*)d_in[2];
  const float* Wk = (const float*)d_in[3];
  const float* bk = (const float*)d_in[4];
  const float* Wv = (const float*)d_in[5];
  const float* bv = (const float*)d_in[6];
  const float* Wm = (const float*)d_in[7];
  const float* bm = (const float*)d_in[8];
  float* out = (float*)d_out;

  char* ws = (char*)d_ws;
  bf16*  Wall = (bf16*)(ws + OFF_WALL);
  bf16*  Wmb  = (bf16*)(ws + OFF_WMB);
  float* ball = (float*)(ws + OFF_BALL);
  bf16*  xT   = (bf16*)(ws + OFF_XT);
  bf16*  Qt   = (bf16*)(ws + OFF_QT);
  bf16*  Kt   = (bf16*)(ws + OFF_KT);
  bf16*  Vd   = (bf16*)(ws + OFF_VD);

  bf16* Rp0 = (bf16*)(ws + OFF_XT);   // aliases xT (dead after k_proj)
  bf16* Rp1 = (bf16*)(ws + OFF_RP1);
  bf16* Rt  = (bf16*)(ws + OFF_QT);   // aliases Qt (dead after k_attn)

  k_wcvt<<<1027, 256, 0, stream>>>(Wq, Wk, Wv, bq, bk, bv, Wm, Wall, ball, Wmb);
  k_tx<<<dim3(L / 32, CH / 32, 2), dim3(32, 8), 0, stream>>>(x, xT);
  k_proj<<<dim3(16, 12, 2), 256, 0, stream>>>(Wall, ball, xT, Qt, Kt, Vd);

  if (ws_size >= NEED4) {
    bf16*  Rp2 = (bf16*)(ws + OFF_RP2);
    bf16*  Rp3 = (bf16*)(ws + OFF_RP3);
    float* Dp  = (float*)(ws + OFF_DP4);
    float* D0 = Dp, *D1 = Dp + 32768, *D2 = Dp + 65536, *D3 = Dp + 98304;
    k_attn<4><<<512, 256, 0, stream>>>(Qt, Kt, Vd, Rp0, Rp1, Rp2, Rp3, D0, D1, D2, D3);
    k_comb<4><<<1024, 256, 0, stream>>>(Rp0, Rp1, Rp2, Rp3, D0, D1, D2, D3, Rt);
  } else {
    float* Dp = (float*)(ws + OFF_DP2);
    float* D0 = Dp, *D1 = Dp + 32768;
    k_attn<2><<<256, 256, 0, stream>>>(Qt, Kt, Vd, Rp0, Rp1, nullptr, nullptr, D0, D1, nullptr, nullptr);
    k_comb<2><<<1024, 256, 0, stream>>>(Rp0, Rp1, nullptr, nullptr, D0, D1, nullptr, nullptr, Rt);
  }

  k_out<<<dim3(64, 2), 256, 0, stream>>>(Wmb, Rt, x, bm, out);
}

// Round 4
// 90.817 us; speedup vs baseline: 3.1049x; 1.1786x over previous
//
#include <hip/hip_runtime.h>
#include <hip/hip_bf16.h>
#include <cstdint>
#include <cstddef>

typedef __bf16 bf16;
typedef bf16 bf16x8 __attribute__((ext_vector_type(8)));
typedef bf16 bf16x4 __attribute__((ext_vector_type(4)));
typedef bf16 bf16x2 __attribute__((ext_vector_type(2)));
typedef float f32x4 __attribute__((ext_vector_type(4)));
typedef float f32x16 __attribute__((ext_vector_type(16)));

#define MFMA16(A, B, Cc) __builtin_amdgcn_mfma_f32_16x16x32_bf16((A), (B), (Cc), 0, 0, 0)
#define MFMA32(A, B, Cc) __builtin_amdgcn_mfma_f32_32x32x16_bf16((A), (B), (Cc), 0, 0, 0)
#define GLD16(g, l)                                                          \
  __builtin_amdgcn_global_load_lds(                                          \
      (const __attribute__((address_space(1))) void*)(g),                    \
      (__attribute__((address_space(3))) void*)(l), 16, 0, 0)

static constexpr int L   = 4096;  // H*W
static constexpr int CH  = 256;   // channels
static constexpr int NH  = 4;     // heads

// workspace layout (bytes), all 16B aligned
static constexpr size_t OFF_WALL = 0;         // 768*256 bf16
static constexpr size_t OFF_WMB  = 393216;    // 256*256 bf16
static constexpr size_t OFF_BALL = 524288;    // 768 f32 (+pad)
static constexpr size_t OFF_XT   = 528384;    // [B][L][C] bf16 (4MB) -- Rp0 aliases after k_proj
static constexpr size_t OFF_QT   = 4722688;   // [B][H][L][64] bf16 (4MB)
static constexpr size_t OFF_KT   = 8916992;   // [B][H][L][64] bf16 (4MB)
static constexpr size_t OFF_VD   = 13111296;  // [B][H][64][L] bf16 (4MB, j-bits-2/3-swapped)
static constexpr size_t OFF_RP1  = 17305600;  // partial R js=1 (4MB)
static constexpr size_t OFF_RP2  = 21499904;  // partial R js=2 (4MB)
static constexpr size_t OFF_RP3  = 25694208;  // partial R js=3 (4MB)
static constexpr size_t OFF_DP4  = 29888512;  // 4 x [8][4096] f32 denoms (512KB)
static constexpr size_t OFF_DP2  = 21499904;  // JS=2: denoms after RP1
static constexpr size_t NEED4    = 30412800;

// ---------------- kernel 0: weight/bias convert + x transpose (merged) -------
__global__ __launch_bounds__(256) void k_prep(
    const float* __restrict__ Wq, const float* __restrict__ Wk,
    const float* __restrict__ Wv, const float* __restrict__ bq,
    const float* __restrict__ bk, const float* __restrict__ bv,
    const float* __restrict__ Wm, const float* __restrict__ x,
    bf16* __restrict__ Wall, float* __restrict__ ball,
    bf16* __restrict__ Wmb, bf16* __restrict__ xT) {
  __shared__ float t[32][33];
  const int bid = blockIdx.x;
  const int tid = threadIdx.x;
  if (bid < 1027) {
    int id = bid * 256 + tid;
    if (id < 65536)        Wall[id] = (bf16)Wq[id];
    else if (id < 131072)  Wall[id] = (bf16)Wk[id - 65536];
    else if (id < 196608)  Wall[id] = (bf16)Wv[id - 131072];
    else if (id < 262144)  Wmb[id - 196608] = (bf16)Wm[id - 196608];
    else if (id < 262912) {
      int k = id - 262144;
      ball[k] = (k < 256) ? bq[k] : (k < 512) ? bk[k - 256] : bv[k - 512];
    }
  } else {
    const int id = bid - 1027;          // 0..2047
    const int b = id >> 10;
    const int c0 = ((id >> 7) & 7) * 32;
    const int l0 = (id & 127) * 32;
    const int tx = tid & 31, ty = tid >> 5;
    #pragma unroll
    for (int i = 0; i < 4; ++i) {
      int c = c0 + ty + 8 * i;
      t[ty + 8 * i][tx] = x[((size_t)b * CH + c) * L + l0 + tx];
    }
    __syncthreads();
    #pragma unroll
    for (int i = 0; i < 4; ++i) {
      int l = l0 + ty + 8 * i;
      xT[((size_t)b * L + l) * CH + c0 + tx] = (bf16)t[tx][ty + 8 * i];
    }
  }
}

// ---------------- kernel 2: fused QKV projection + L2 norm ----------------
// V stored with j-bits 2<->3 swapped along L (so k_attn's PV A-frag is a
// straight register pack of the QK output -- see k_attn).
__global__ __launch_bounds__(256) void k_proj(
    const bf16* __restrict__ Wall, const float* __restrict__ ball,
    const bf16* __restrict__ xT, bf16* __restrict__ Qt,
    bf16* __restrict__ Kt, bf16* __restrict__ Vd) {
  const int b = blockIdx.z, strip = blockIdx.y, lt = blockIdx.x;
  const int w = threadIdx.x >> 6;
  const int lane = threadIdx.x & 63;
  const int lo = lane & 15, g = lane >> 4;
  const int l0 = lt * 256 + w * 64;

  const bf16* wbase = Wall + (size_t)strip * 64 * CH;
  const bf16* xbase = xT + (size_t)b * L * CH;

  f32x4 acc[4][4];
  #pragma unroll
  for (int m = 0; m < 4; ++m)
    #pragma unroll
    for (int n = 0; n < 4; ++n) acc[m][n] = (f32x4){0.f, 0.f, 0.f, 0.f};

  #pragma unroll
  for (int kc = 0; kc < 8; ++kc) {
    bf16x8 aw[4], bx[4];
    #pragma unroll
    for (int m = 0; m < 4; ++m)
      aw[m] = *(const bf16x8*)(wbase + (size_t)(16 * m + lo) * CH + kc * 32 + g * 8);
    #pragma unroll
    for (int n = 0; n < 4; ++n)
      bx[n] = *(const bf16x8*)(xbase + (size_t)(l0 + 16 * n + lo) * CH + kc * 32 + g * 8);
    #pragma unroll
    for (int m = 0; m < 4; ++m)
      #pragma unroll
      for (int n = 0; n < 4; ++n) acc[m][n] = MFMA16(aw[m], bx[n], acc[m][n]);
  }

  #pragma unroll
  for (int m = 0; m < 4; ++m)
    #pragma unroll
    for (int r = 0; r < 4; ++r) {
      float bias = ball[strip * 64 + 16 * m + 4 * g + r];
      #pragma unroll
      for (int n = 0; n < 4; ++n) acc[m][n][r] += bias;
    }

  if (strip < 8) {
    #pragma unroll
    for (int n = 0; n < 4; ++n) {
      float ss = 0.f;
      #pragma unroll
      for (int m = 0; m < 4; ++m)
        #pragma unroll
        for (int r = 0; r < 4; ++r) ss += acc[m][n][r] * acc[m][n][r];
      ss += __shfl_xor(ss, 16);
      ss += __shfl_xor(ss, 32);
      float sc = 1.f / fmaxf(sqrtf(ss), 1e-6f);
      #pragma unroll
      for (int m = 0; m < 4; ++m)
        #pragma unroll
        for (int r = 0; r < 4; ++r) acc[m][n][r] *= sc;
    }
    bf16* dst = (strip < 4) ? Qt : Kt;
    const int h = strip & 3;
    #pragma unroll
    for (int n = 0; n < 4; ++n) {
      const int l = l0 + 16 * n + lo;
      #pragma unroll
      for (int m = 0; m < 4; ++m) {
        size_t base = ((size_t)(b * NH + h) * L + l) * 64 + 16 * m + 4 * g;
        bf16x2 v01, v23;
        v01[0] = (bf16)acc[m][n][0]; v01[1] = (bf16)acc[m][n][1];
        v23[0] = (bf16)acc[m][n][2]; v23[1] = (bf16)acc[m][n][3];
        *(bf16x2*)(dst + base)     = v01;
        *(bf16x2*)(dst + base + 2) = v23;
      }
    }
  } else {
    const int h = strip - 8;
    const int lop = (lo & 3) | ((lo & 4) << 1) | ((lo & 8) >> 1);  // swap bits 2,3
    #pragma unroll
    for (int m = 0; m < 4; ++m)
      #pragma unroll
      for (int r = 0; r < 4; ++r) {
        const int d = 16 * m + 4 * g + r;
        #pragma unroll
        for (int n = 0; n < 4; ++n) {
          const int l = l0 + 16 * n + lop;
          Vd[((size_t)(b * NH + h) * 64 + d) * L + l] = (bf16)acc[m][n][r];
        }
      }
  }
}

// ---------------- kernel 3: attention (32x32 MFMA, in-register P) -----------
// 4 waves x 64 q = 256 q/block. K [j][d] and V [dv][j'] staged in LDS via
// global_load_lds (linear dest, inverse-swizzled source, swizzled ds_read).
// Swapped QK (A=K, B=Q): lane owns q-col = lane&31; 16 regs = 16 j's. V's
// j-axis is bit-2/3-swapped so PV A-frags = pack of consecutive p regs.
// j split JS ways across blocks; unnormalized bf16 partials + f32 denom.

#define STAGE(bb, j0)                                                          \
  {                                                                            \
    const char* gk0 = kbase + (size_t)((j0) + sr) * 128 + scS;                 \
    const char* gk1 = kbase + (size_t)((j0) + 32 + sr) * 128 + scS;            \
    const char* gv0 = vbase + (size_t)sr * 8192 + (size_t)(j0) * 2 + scS;      \
    const char* gv1 = vbase + (size_t)(32 + sr) * 8192 + (size_t)(j0) * 2 + scS; \
    GLD16(gk0, kbuf[bb] + tid * 16);                                           \
    GLD16(gk1, kbuf[bb] + 4096 + tid * 16);                                    \
    GLD16(gv0, vbuf[bb] + tid * 16);                                           \
    GLD16(gv1, vbuf[bb] + 4096 + tid * 16);                                    \
  }

#define COMPUTE(bb)                                                            \
  {                                                                            \
    const char* kb = kbuf[bb];                                                 \
    const char* vb = vbuf[bb];                                                 \
    _Pragma("unroll") for (int jb = 0; jb < 2; ++jb) {                         \
      bf16x8 kf[4], vf[2][2];                                                  \
      _Pragma("unroll") for (int f = 0; f < 4; ++f)                            \
        kf[f] = *(const bf16x8*)(kb + (32 * jb + ln) * 128 +                   \
                                 ((32 * f + 16 * hi) ^ sw));                   \
      _Pragma("unroll") for (int dvb = 0; dvb < 2; ++dvb)                      \
        _Pragma("unroll") for (int c = 0; c < 2; ++c)                          \
          vf[dvb][c] = *(const bf16x8*)(vb + (32 * dvb + ln) * 128 +           \
                                        ((64 * jb + 32 * c + 16 * hi) ^ sw));  \
      _Pragma("unroll") for (int qb = 0; qb < 2; ++qb) {                       \
        f32x16 z;                                                              \
        _Pragma("unroll") for (int r = 0; r < 16; ++r) z[r] = 0.f;             \
        _Pragma("unroll") for (int f = 0; f < 4; ++f)                          \
          z = MFMA32(kf[f], qf[qb][f], z);                                     \
        float p[16];                                                           \
        _Pragma("unroll") for (int r = 0; r < 16; ++r) p[r] = __expf(z[r]);    \
        float t0 = (p[0] + p[1]) + (p[2] + p[3]);                              \
        float t1 = (p[4] + p[5]) + (p[6] + p[7]);                              \
        float t2 = (p[8] + p[9]) + (p[10] + p[11]);                            \
        float t3 = (p[12] + p[13]) + (p[14] + p[15]);                          \
        den[qb] += (t0 + t1) + (t2 + t3);                                      \
        bf16x8 pf0, pf1;                                                       \
        _Pragma("unroll") for (int e = 0; e < 8; ++e) {                        \
          pf0[e] = (bf16)p[e];                                                 \
          pf1[e] = (bf16)p[8 + e];                                             \
        }                                                                      \
        _Pragma("unroll") for (int dvb = 0; dvb < 2; ++dvb) {                  \
          racc[qb][dvb] = MFMA32(pf0, vf[dvb][0], racc[qb][dvb]);              \
          racc[qb][dvb] = MFMA32(pf1, vf[dvb][1], racc[qb][dvb]);              \
        }                                                                      \
      }                                                                        \
    }                                                                          \
  }

template <int JS>
__global__ __launch_bounds__(256, 2) void k_attn(
    const bf16* __restrict__ Qt, const bf16* __restrict__ Kt,
    const bf16* __restrict__ Vd, bf16* __restrict__ R0,
    bf16* __restrict__ R1, bf16* __restrict__ R2, bf16* __restrict__ R3,
    float* __restrict__ D0, float* __restrict__ D1,
    float* __restrict__ D2, float* __restrict__ D3) {
  const int id = blockIdx.x;
  const int bh = id & 7;
  const int qt = (id >> 3) & 15;
  const int js = id >> 7;
  const int tid = threadIdx.x;
  const int w = tid >> 6;
  const int lane = tid & 63;
  const int ln = lane & 31, hi = lane >> 5;
  const int sw = (ln & 7) << 4;
  const int i0 = qt * 256 + w * 64;

  __shared__ __align__(16) char kbuf[2][8192];
  __shared__ __align__(16) char vbuf[2][8192];

  const char* kbase = (const char*)(Kt + (size_t)bh * L * 64);
  const char* vbase = (const char*)(Vd + (size_t)bh * 64 * L);

  const int sr = tid >> 3;
  const int sc = (tid & 7) * 16;
  const int scS = sc ^ ((sr & 7) << 4);

  // Q B-frags: qf[qb][f] = Q[i0+32qb+ln][16f+8hi .. +7]
  const bf16* qbp = Qt + ((size_t)bh * L + i0) * 64;
  bf16x8 qf[2][4];
  #pragma unroll
  for (int qb = 0; qb < 2; ++qb)
    #pragma unroll
    for (int f = 0; f < 4; ++f)
      qf[qb][f] = *(const bf16x8*)(qbp + (size_t)(32 * qb + ln) * 64 + 16 * f + 8 * hi);

  f32x16 racc[2][2];
  #pragma unroll
  for (int qb = 0; qb < 2; ++qb)
    #pragma unroll
    for (int dvb = 0; dvb < 2; ++dvb)
      #pragma unroll
      for (int r = 0; r < 16; ++r) racc[qb][dvb][r] = 0.f;
  float den[2] = {0.f, 0.f};

  const int jbeg = js * (L / JS);
  const int nt = (L / JS) / 64;

  STAGE(0, jbeg)
  __syncthreads();
  for (int it = 0; it < nt; ++it) {
    const int bb = it & 1;
    if (it + 1 < nt) STAGE(bb ^ 1, jbeg + (it + 1) * 64)
    COMPUTE(bb)
    __syncthreads();  // drains stage vmcnt + guards buffer reuse
  }

  // full denominator: lane-local sum covers its hi-half of j; add the other.
  #pragma unroll
  for (int qb = 0; qb < 2; ++qb) den[qb] += __shfl_xor(den[qb], 32);

  bf16* rp = (js == 0) ? R0 : (js == 1) ? R1 : (js == 2) ? R2 : R3;
  float* dp = (js == 0) ? D0 : (js == 1) ? D1 : (js == 2) ? D2 : D3;

  if (hi == 0) {
    #pragma unroll
    for (int qb = 0; qb < 2; ++qb)
      dp[(size_t)bh * L + i0 + 32 * qb + ln] = den[qb];
  }
  #pragma unroll
  for (int qb = 0; qb < 2; ++qb)
    #pragma unroll
    for (int dvb = 0; dvb < 2; ++dvb)
      #pragma unroll
      for (int r = 0; r < 16; ++r) {
        const int q = 32 * qb + (r & 3) + 8 * (r >> 2) + 4 * hi;
        rp[((size_t)bh * L + i0 + q) * 64 + 32 * dvb + ln] = (bf16)racc[qb][dvb][r];
      }
}

// ---------------- kernel 4: output projection + combine + bias + residual ----
// B-frags built on the fly from the JS unnormalized partials + denominators.
template <int JS>
__global__ __launch_bounds__(256) void k_out(
    const bf16* __restrict__ Wmb, const bf16* __restrict__ R0,
    const bf16* __restrict__ R1, const bf16* __restrict__ R2,
    const bf16* __restrict__ R3, const float* __restrict__ D0,
    const float* __restrict__ D1, const float* __restrict__ D2,
    const float* __restrict__ D3, const float* __restrict__ x,
    const float* __restrict__ bm, float* __restrict__ out) {
  const int b = blockIdx.y, lt = blockIdx.x;  // 128 l-tiles of 32
  const int w = threadIdx.x >> 6;
  const int lane = threadIdx.x & 63;
  const int lo = lane & 15, g = lane >> 4;
  const int o0 = w * 64, l0 = lt * 32;

  float invd[2][4];
  #pragma unroll
  for (int n = 0; n < 2; ++n) {
    const int l = l0 + 16 * n + lo;
    #pragma unroll
    for (int h = 0; h < 4; ++h) {
      const size_t di = (size_t)(b * NH + h) * L + l;
      float dd = D0[di] + D1[di];
      if (JS == 4) dd += D2[di] + D3[di];
      invd[n][h] = 1.0f / dd;
    }
  }

  f32x4 acc[4][2];
  #pragma unroll
  for (int m = 0; m < 4; ++m)
    #pragma unroll
    for (int n = 0; n < 2; ++n) acc[m][n] = (f32x4){0.f, 0.f, 0.f, 0.f};

  #pragma unroll
  for (int kc = 0; kc < 8; ++kc) {
    bf16x8 aw[4], bx[2];
    #pragma unroll
    for (int m = 0; m < 4; ++m)
      aw[m] = *(const bf16x8*)(Wmb + (size_t)(o0 + 16 * m + lo) * CH + kc * 32 + g * 8);
    const int h = kc >> 1;
    #pragma unroll
    for (int n = 0; n < 2; ++n) {
      const size_t base = ((size_t)(b * NH + h) * L + (l0 + 16 * n + lo)) * 64 +
                          (kc & 1) * 32 + 8 * g;
      bf16x8 r0 = *(const bf16x8*)(R0 + base);
      bf16x8 r1 = *(const bf16x8*)(R1 + base);
      const float iv = invd[n][h];
      if (JS == 4) {
        bf16x8 r2 = *(const bf16x8*)(R2 + base);
        bf16x8 r3 = *(const bf16x8*)(R3 + base);
        #pragma unroll
        for (int e = 0; e < 8; ++e) {
          float s = ((float)r0[e] + (float)r1[e]) + ((float)r2[e] + (float)r3[e]);
          bx[n][e] = (bf16)(s * iv);
        }
      } else {
        #pragma unroll
        for (int e = 0; e < 8; ++e)
          bx[n][e] = (bf16)(((float)r0[e] + (float)r1[e]) * iv);
      }
    }
    #pragma unroll
    for (int m = 0; m < 4; ++m)
      #pragma unroll
      for (int n = 0; n < 2; ++n) acc[m][n] = MFMA16(aw[m], bx[n], acc[m][n]);
  }

  #pragma unroll
  for (int m = 0; m < 4; ++m)
    #pragma unroll
    for (int r = 0; r < 4; ++r) {
      const int o = o0 + 16 * m + 4 * g + r;
      const float bias = bm[o];
      #pragma unroll
      for (int n = 0; n < 2; ++n) {
        const int l = l0 + 16 * n + lo;
        size_t idx = ((size_t)b * CH + o) * (size_t)L + l;
        out[idx] = acc[m][n][r] + bias + x[idx];
      }
    }
}

// ---------------- launcher ----------------
extern "C" void kernel_launch(void* const* d_in, const int* in_sizes, int n_in,
                              void* d_out, int out_size, void* d_ws, size_t ws_size,
                              hipStream_t stream) {
  const float* x  = (const float*)d_in[0];
  const float* Wq = (const float*)d_in[1];
  const float* bq = (const float*)d_in[2];
  const float* Wk = (const float*)d_in[3];
  const float* bk = (const float*)d_in[4];
  const float* Wv = (const float*)d_in[5];
  const float* bv = (const float*)d_in[6];
  const float* Wm = (const float*)d_in[7];
  const float* bm = (const float*)d_in[8];
  float* out = (float*)d_out;

  char* ws = (char*)d_ws;
  bf16*  Wall = (bf16*)(ws + OFF_WALL);
  bf16*  Wmb  = (bf16*)(ws + OFF_WMB);
  float* ball = (float*)(ws + OFF_BALL);
  bf16*  xT   = (bf16*)(ws + OFF_XT);
  bf16*  Qt   = (bf16*)(ws + OFF_QT);
  bf16*  Kt   = (bf16*)(ws + OFF_KT);
  bf16*  Vd   = (bf16*)(ws + OFF_VD);

  bf16* Rp0 = (bf16*)(ws + OFF_XT);   // aliases xT (dead after k_proj)
  bf16* Rp1 = (bf16*)(ws + OFF_RP1);

  k_prep<<<3075, 256, 0, stream>>>(Wq, Wk, Wv, bq, bk, bv, Wm, x, Wall, ball, Wmb, xT);
  k_proj<<<dim3(16, 12, 2), 256, 0, stream>>>(Wall, ball, xT, Qt, Kt, Vd);

  if (ws_size >= NEED4) {
    bf16*  Rp2 = (bf16*)(ws + OFF_RP2);
    bf16*  Rp3 = (bf16*)(ws + OFF_RP3);
    float* Dp  = (float*)(ws + OFF_DP4);
    float* D0 = Dp, *D1 = Dp + 32768, *D2 = Dp + 65536, *D3 = Dp + 98304;
    k_attn<4><<<512, 256, 0, stream>>>(Qt, Kt, Vd, Rp0, Rp1, Rp2, Rp3, D0, D1, D2, D3);
    k_out<4><<<dim3(128, 2), 256, 0, stream>>>(Wmb, Rp0, Rp1, Rp2, Rp3, D0, D1, D2, D3,
                                               x, bm, out);
  } else {
    float* Dp = (float*)(ws + OFF_DP2);
    float* D0 = Dp, *D1 = Dp + 32768;
    k_attn<2><<<256, 256, 0, stream>>>(Qt, Kt, Vd, Rp0, Rp1, nullptr, nullptr,
                                       D0, D1, nullptr, nullptr);
    k_out<2><<<dim3(128, 2), 256, 0, stream>>>(Wmb, Rp0, Rp1, nullptr, nullptr,
                                               D0, D1, nullptr, nullptr, x, bm, out);
  }
}